// Round 1
// baseline (174.347 us; speedup 1.0000x reference)
//
#include <hip/hip_runtime.h>
#include <hip/hip_bf16.h>
#include <cstdio>

typedef float f32x4 __attribute__((ext_vector_type(4)));
typedef __bf16 bf16x8 __attribute__((ext_vector_type(8)));

static constexpr int Bn = 8, Nn = 2048, Dn = 512, Hn = 512;

__device__ __forceinline__ unsigned short f2bf(float x) {
    union { float f; unsigned int u; } v; v.f = x;
    unsigned int r = (v.u + 0x7FFFu + ((v.u >> 16) & 1u)) >> 16;
    return (unsigned short)r;
}
__device__ __forceinline__ float bf2f(unsigned short h) {
    union { unsigned int u; float f; } v; v.u = ((unsigned int)h) << 16;
    return v.f;
}

// ---------------- cast x (f32 -> bf16), flat ----------------
__global__ void cast_x_kernel(const float* __restrict__ x, unsigned short* __restrict__ xb, int n) {
    int i = (blockIdx.x * blockDim.x + threadIdx.x) * 8;
    if (i >= n) return;
    float4 a = *(const float4*)(x + i);
    float4 b = *(const float4*)(x + i + 4);
    unsigned short tmp[8] = {f2bf(a.x), f2bf(a.y), f2bf(a.z), f2bf(a.w),
                             f2bf(b.x), f2bf(b.y), f2bf(b.z), f2bf(b.w)};
    *(uint4*)(xb + i) = *(const uint4*)tmp;
}

// ---- transpose + cast (+ optional per-input-row divide): in f32 [R][C] -> out bf16 [C][R] ----
__global__ __launch_bounds__(256) void transpose_cast_kernel(
    const float* __restrict__ in, unsigned short* __restrict__ out,
    const float* __restrict__ sdiv, int R, int C)
{
    __shared__ float tile[64][65];
    const int z = blockIdx.z;
    const float* inb = in + (size_t)z * R * C;
    unsigned short* outb = out + (size_t)z * R * C;
    const int r0 = blockIdx.y * 64, c0 = blockIdx.x * 64;
    const int tx = threadIdx.x & 63, ty = threadIdx.x >> 6;
#pragma unroll
    for (int p = 0; p < 64; p += 4) {
        const int r = p + ty;
        float v = inb[(size_t)(r0 + r) * C + c0 + tx];
        if (sdiv) v /= sdiv[(size_t)z * R + r0 + r];
        tile[r][tx] = v;
    }
    __syncthreads();
#pragma unroll
    for (int p = 0; p < 64; p += 4) {
        const int oc = p + ty;
        outb[(size_t)(c0 + oc) * R + r0 + tx] = f2bf(tile[tx][oc]);
    }
}

// ---------------- combine per-block partial column sums ----------------
__global__ void combine_s_kernel(const float* __restrict__ s_part, float* __restrict__ s,
                                 int nblk, int total) {
    int i = blockIdx.x * blockDim.x + threadIdx.x;
    if (i >= total) return;
    int z = i >> 11, j = i & (Nn - 1);
    float acc = 0.f;
    for (int p = 0; p < nblk; ++p) acc += s_part[((size_t)z * nblk + p) * Nn + j];
    s[i] = acc;
}

// ---------------- generic C = A * B^T tile GEMM (bf16 MFMA) ----------------
// A: [M][K] bf16 row-major (+z*sA), Bt: [N][K] bf16 row-major (+z*sB)
// MODE 0: C bf16 [M][N], += bias[col]
// MODE 1: C bf16 = exp(acc), also write per-column partial sums s_part[z][gridDim.y][N]
// MODE 2: C f32 [M][N]
template<int MODE>
__global__ __launch_bounds__(256, 2) void gemm_bt(
    const unsigned short* __restrict__ A, long long sA,
    const unsigned short* __restrict__ Bt, long long sB,
    void* __restrict__ Cp, long long sC,
    const float* __restrict__ bias,
    float* __restrict__ s_part,
    int M, int N, int K)
{
    __shared__ unsigned short As[128 * 64];
    __shared__ unsigned short Bs[128 * 64];
    __shared__ float s_red[256];

    const int z = blockIdx.z;
    const unsigned short* Ab = A + (size_t)z * sA;
    const unsigned short* Bb = Bt + (size_t)z * sB;
    const int i0 = blockIdx.y * 128, j0 = blockIdx.x * 128;

    const int t = threadIdx.x;
    const int lane = t & 63;
    const int wave = t >> 6;
    const int wr = wave >> 1, wc = wave & 1;
    const int l15 = lane & 15, g = lane >> 4;

    f32x4 acc[4][4];
    const f32x4 zero4 = {0.f, 0.f, 0.f, 0.f};
#pragma unroll
    for (int mi = 0; mi < 4; ++mi)
#pragma unroll
        for (int ni = 0; ni < 4; ++ni) acc[mi][ni] = zero4;

    const int srow = t >> 3;   // 0..31
    const int sslot = t & 7;   // 0..7  (16B chunk within a 64-elem row)

    for (int kt = 0; kt < K; kt += 64) {
#pragma unroll
        for (int rep = 0; rep < 4; ++rep) {
            const int row = srow + 32 * rep;
            const int wsl = (sslot ^ (row & 7)) * 8;  // XOR swizzle: conflict-free b128
            const uint4 av = *(const uint4*)(Ab + (size_t)(i0 + row) * K + kt + sslot * 8);
            *(uint4*)(As + row * 64 + wsl) = av;
            const uint4 bv = *(const uint4*)(Bb + (size_t)(j0 + row) * K + kt + sslot * 8);
            *(uint4*)(Bs + row * 64 + wsl) = bv;
        }
        __syncthreads();
#pragma unroll
        for (int kk = 0; kk < 64; kk += 32) {
            const int sl0 = (kk >> 3) + g;  // our k-bijection: lane g holds k = kk + 8g .. +7 (same for A and B)
            bf16x8 af[4], bfr[4];
#pragma unroll
            for (int mi = 0; mi < 4; ++mi) {
                const int row = wr * 64 + mi * 16 + l15;
                af[mi] = *(const bf16x8*)(As + row * 64 + ((sl0 ^ (row & 7)) * 8));
            }
#pragma unroll
            for (int ni = 0; ni < 4; ++ni) {
                const int row = wc * 64 + ni * 16 + l15;
                bfr[ni] = *(const bf16x8*)(Bs + row * 64 + ((sl0 ^ (row & 7)) * 8));
            }
#pragma unroll
            for (int mi = 0; mi < 4; ++mi)
#pragma unroll
                for (int ni = 0; ni < 4; ++ni)
                    acc[mi][ni] = __builtin_amdgcn_mfma_f32_16x16x32_bf16(af[mi], bfr[ni], acc[mi][ni], 0, 0, 0);
        }
        __syncthreads();
    }

    if (MODE == 0) {
        unsigned short* C = (unsigned short*)Cp;
#pragma unroll
        for (int ni = 0; ni < 4; ++ni) {
            const int col = j0 + wc * 64 + ni * 16 + l15;
            const float bv = bias[col];
#pragma unroll
            for (int mi = 0; mi < 4; ++mi) {
                const int rb = i0 + wr * 64 + mi * 16 + g * 4;
#pragma unroll
                for (int r = 0; r < 4; ++r)
                    C[(size_t)(rb + r) * N + col] = f2bf(acc[mi][ni][r] + bv);
            }
        }
    } else if (MODE == 1) {
        unsigned short* C = (unsigned short*)Cp + (size_t)z * sC;
        float cs[4] = {0.f, 0.f, 0.f, 0.f};
#pragma unroll
        for (int ni = 0; ni < 4; ++ni) {
            const int col = j0 + wc * 64 + ni * 16 + l15;
#pragma unroll
            for (int mi = 0; mi < 4; ++mi) {
                const int rb = i0 + wr * 64 + mi * 16 + g * 4;
#pragma unroll
                for (int r = 0; r < 4; ++r) {
                    const float e = __expf(acc[mi][ni][r]);
                    const unsigned short h = f2bf(e);
                    C[(size_t)(rb + r) * N + col] = h;
                    cs[ni] += bf2f(h);   // sum the rounded value for numerator/denominator consistency
                }
            }
        }
#pragma unroll
        for (int ni = 0; ni < 4; ++ni) {
            cs[ni] += __shfl_xor(cs[ni], 16);
            cs[ni] += __shfl_xor(cs[ni], 32);
        }
        if (g == 0) {
#pragma unroll
            for (int ni = 0; ni < 4; ++ni)
                s_red[wr * 128 + wc * 64 + ni * 16 + l15] = cs[ni];
        }
        __syncthreads();
        if (t < 128) {
            const float sp = s_red[t] + s_red[128 + t];
            s_part[((size_t)z * gridDim.y + blockIdx.y) * N + j0 + t] = sp;
        }
    } else {
        float* C = (float*)Cp + (size_t)z * sC;
#pragma unroll
        for (int ni = 0; ni < 4; ++ni) {
            const int col = j0 + wc * 64 + ni * 16 + l15;
#pragma unroll
            for (int mi = 0; mi < 4; ++mi) {
                const int rb = i0 + wr * 64 + mi * 16 + g * 4;
#pragma unroll
                for (int r = 0; r < 4; ++r)
                    C[(size_t)(rb + r) * N + col] = acc[mi][ni][r];
            }
        }
    }
}

extern "C" void kernel_launch(void* const* d_in, const int* in_sizes, int n_in,
                              void* d_out, int out_size, void* d_ws, size_t ws_size,
                              hipStream_t stream) {
    const float* x  = (const float*)d_in[0];
    const float* Wq = (const float*)d_in[1];
    const float* bq = (const float*)d_in[2];
    const float* Wk = (const float*)d_in[3];
    const float* bk = (const float*)d_in[4];
    float* out = (float*)d_out;

    char* ws = (char*)d_ws;
    unsigned short* xb    = (unsigned short*)(ws);                               // 16 MB
    unsigned short* q     = (unsigned short*)(ws + (16ull << 20));               // 16 MB
    unsigned short* k     = (unsigned short*)(ws + (32ull << 20));               // 16 MB
    unsigned short* WqT   = (unsigned short*)(ws + (48ull << 20));               // 0.5 MB
    unsigned short* WkT   = (unsigned short*)(ws + (48ull << 20) + (1ull << 19));// 0.5 MB
    unsigned short* xsT   = (unsigned short*)(ws + (49ull << 20));               // 16 MB
    float*          s_prt = (float*)(ws + (65ull << 20));                        // 1 MB
    float*          s     = (float*)(ws + (66ull << 20));                        // 64 KB
    unsigned short* expE  = (unsigned short*)(ws + (67ull << 20));               // 64 MB
    if (ws_size < (131ull << 20)) {
        fprintf(stderr, "WS TOO SMALL: have %zu need %llu\n", ws_size, (131ull << 20));
    }

    // 1) xb = bf16(x)
    cast_x_kernel<<<dim3((Bn * Nn * Dn) / (8 * 256)), 256, 0, stream>>>(x, xb, Bn * Nn * Dn);
    // 2) WqT/WkT = bf16(W^T)
    transpose_cast_kernel<<<dim3(Hn / 64, Dn / 64, 1), 256, 0, stream>>>(Wq, WqT, nullptr, Dn, Hn);
    transpose_cast_kernel<<<dim3(Hn / 64, Dn / 64, 1), 256, 0, stream>>>(Wk, WkT, nullptr, Dn, Hn);
    // 3) q/k = xb @ W + b   (M=16384, N=512, K=512)
    gemm_bt<0><<<dim3(Hn / 128, (Bn * Nn) / 128, 1), 256, 0, stream>>>(
        xb, 0, WqT, 0, q, 0, bq, nullptr, Bn * Nn, Hn, Dn);
    gemm_bt<0><<<dim3(Hn / 128, (Bn * Nn) / 128, 1), 256, 0, stream>>>(
        xb, 0, WkT, 0, k, 0, bk, nullptr, Bn * Nn, Hn, Dn);
    // 4) expE = exp(q @ k^T), s_part (per batch; M=N=2048, K=512)
    gemm_bt<1><<<dim3(Nn / 128, Nn / 128, Bn), 256, 0, stream>>>(
        q, (long long)Nn * Hn, k, (long long)Nn * Hn, expE, (long long)Nn * Nn,
        nullptr, s_prt, Nn, Nn, Hn);
    // 5) s[b][j] = sum of partials
    combine_s_kernel<<<dim3((Bn * Nn) / 256), 256, 0, stream>>>(s_prt, s, Nn / 128, Bn * Nn);
    // 6) xsT[b][d][j] = bf16(x[b][j][d] / s[b][j])
    transpose_cast_kernel<<<dim3(Dn / 64, Nn / 64, Bn), 256, 0, stream>>>(x, xsT, s, Nn, Dn);
    // 7) out = expE @ xsT^T   (per batch; M=2048, N=512, K=2048)
    gemm_bt<2><<<dim3(Dn / 128, Nn / 128, Bn), 256, 0, stream>>>(
        expE, (long long)Nn * Nn, xsT, (long long)Dn * Nn, out, (long long)Nn * Dn,
        nullptr, nullptr, Nn, Dn, Nn);
}

// Round 2
// 145.459 us; speedup vs baseline: 1.1986x; 1.1986x over previous
//
#include <hip/hip_runtime.h>
#include <hip/hip_bf16.h>
#include <cstdio>

typedef float f32x4 __attribute__((ext_vector_type(4)));
typedef __bf16 bf16x8 __attribute__((ext_vector_type(8)));

static constexpr int Bn = 8, Nn = 2048, Dn = 512, Hn = 512;

__device__ __forceinline__ unsigned short f2bf(float x) {
    union { float f; unsigned int u; } v; v.f = x;
    unsigned int r = (v.u + 0x7FFFu + ((v.u >> 16) & 1u)) >> 16;
    return (unsigned short)r;
}
__device__ __forceinline__ float bf2f(unsigned short h) {
    union { unsigned int u; float f; } v; v.u = ((unsigned int)h) << 16;
    return v.f;
}

// async global->LDS, 16B per lane; LDS dest is wave-uniform base + lane*16
__device__ __forceinline__ void gload_lds16(const unsigned short* g, unsigned short* l) {
    __builtin_amdgcn_global_load_lds(
        (const __attribute__((address_space(1))) void*)g,
        (__attribute__((address_space(3))) void*)l,
        16, 0, 0);
}

__device__ __forceinline__ int xcd_swizzle(int lin, int nwg) {
    // nwg % 8 == 0 for all our grids -> simple bijective form
    return (lin & 7) * (nwg >> 3) + (lin >> 3);
}

// ---------------- cast x (f32 -> bf16), flat ----------------
__global__ void cast_x_kernel(const float* __restrict__ x, unsigned short* __restrict__ xb, int n) {
    int i = (blockIdx.x * blockDim.x + threadIdx.x) * 8;
    if (i >= n) return;
    float4 a = *(const float4*)(x + i);
    float4 b = *(const float4*)(x + i + 4);
    unsigned short tmp[8] = {f2bf(a.x), f2bf(a.y), f2bf(a.z), f2bf(a.w),
                             f2bf(b.x), f2bf(b.y), f2bf(b.z), f2bf(b.w)};
    *(uint4*)(xb + i) = *(const uint4*)tmp;
}

// ---- transpose + cast (+ optional per-input-row divide): in f32 [R][C] -> out bf16 [C][R] ----
__global__ __launch_bounds__(256) void transpose_cast_kernel(
    const float* __restrict__ in, unsigned short* __restrict__ out,
    const float* __restrict__ sdiv, int R, int C)
{
    __shared__ float tile[64][65];
    const int z = blockIdx.z;
    const float* inb = in + (size_t)z * R * C;
    unsigned short* outb = out + (size_t)z * R * C;
    const int r0 = blockIdx.y * 64, c0 = blockIdx.x * 64;
    const int tx = threadIdx.x & 63, ty = threadIdx.x >> 6;
#pragma unroll
    for (int p = 0; p < 64; p += 4) {
        const int r = p + ty;
        float v = inb[(size_t)(r0 + r) * C + c0 + tx];
        if (sdiv) v /= sdiv[(size_t)z * R + r0 + r];
        tile[r][tx] = v;
    }
    __syncthreads();
#pragma unroll
    for (int p = 0; p < 64; p += 4) {
        const int oc = p + ty;
        outb[(size_t)(c0 + oc) * R + r0 + tx] = f2bf(tile[tx][oc]);
    }
}

// ---------------- combine per-block partial column sums ----------------
__global__ void combine_s_kernel(const float* __restrict__ s_part, float* __restrict__ s,
                                 int nblk, int total) {
    int i = blockIdx.x * blockDim.x + threadIdx.x;
    if (i >= total) return;
    int z = i >> 11, j = i & (Nn - 1);
    float acc = 0.f;
    for (int p = 0; p < nblk; ++p) acc += s_part[((size_t)z * nblk + p) * Nn + j];
    s[i] = acc;
}

// ---------------- generic C = A * B^T tile GEMM (bf16 MFMA) ----------------
// A: [M][lda] bf16 (+z*sA), Bt: [N][ldb] bf16 (+z*sB); 128x128 tile, BK=64,
// global_load_lds w16 staging with pre-swizzled source (LDS written linearly,
// reads use chunk ^= row&7 — same involution on both sides).
// MODE 0: C bf16 [M][N], += bias (split: col<bsplit ? bias : bias2)
// MODE 1: C bf16 = exp(acc), also per-column partial sums s_part[z][gy][N]
// MODE 2: C f32 [M][N]
template<int MODE>
__global__ __launch_bounds__(256, 2) void gemm_bt(
    const unsigned short* __restrict__ A, long long sA, int lda,
    const unsigned short* __restrict__ Bt, long long sB, int ldb,
    void* __restrict__ Cp, long long sC,
    const float* __restrict__ bias, const float* __restrict__ bias2, int bsplit,
    float* __restrict__ s_part,
    int M, int N, int K, int gx, int gy)
{
    __shared__ unsigned short As[128 * 64];
    __shared__ unsigned short Bs[128 * 64];
    __shared__ float s_red[256];

    // XCD-aware bijective block swizzle, then decompose (x fastest)
    const int lin = xcd_swizzle(blockIdx.x, gridDim.x);
    const int bz = lin / (gx * gy);
    const int rem = lin - bz * gx * gy;
    const int by = rem / gx;
    const int bx = rem - by * gx;

    const unsigned short* Ab = A + (size_t)bz * sA;
    const unsigned short* Bb = Bt + (size_t)bz * sB;
    const int i0 = by * 128, j0 = bx * 128;

    const int t = threadIdx.x;
    const int lane = t & 63;
    const int wave = t >> 6;
    const int wr = wave >> 1, wc = wave & 1;
    const int l15 = lane & 15, g = lane >> 4;

    f32x4 acc[4][4];
    const f32x4 zero4 = {0.f, 0.f, 0.f, 0.f};
#pragma unroll
    for (int mi = 0; mi < 4; ++mi)
#pragma unroll
        for (int ni = 0; ni < 4; ++ni) acc[mi][ni] = zero4;

    // staging geometry: each gload_lds instr = 64 lanes x 16B = 1KB = 8 rows of 128B
    const int rbase = wave * 32;                      // this wave's 32 rows of A and B
    const int lrow = lane >> 3;                       // 0..7 row within instr
    const int gch = (lane & 7) ^ lrow;                // pre-swizzled source chunk (involution)

    for (int kt = 0; kt < K; kt += 64) {
#pragma unroll
        for (int i = 0; i < 4; ++i) {
            const int r = rbase + i * 8 + lrow;
            gload_lds16(Ab + (size_t)(i0 + r) * lda + kt + gch * 8, As + (rbase + i * 8) * 64);
            gload_lds16(Bb + (size_t)(j0 + r) * ldb + kt + gch * 8, Bs + (rbase + i * 8) * 64);
        }
        __syncthreads();
#pragma unroll
        for (int kk = 0; kk < 64; kk += 32) {
            const int sl0 = (kk >> 3) + g;  // lane g holds k = kk + 8g .. +7 (same bijection A and B)
            bf16x8 af[4], bfr[4];
#pragma unroll
            for (int mi = 0; mi < 4; ++mi) {
                const int row = wr * 64 + mi * 16 + l15;
                af[mi] = *(const bf16x8*)(As + row * 64 + ((sl0 ^ (row & 7)) * 8));
            }
#pragma unroll
            for (int ni = 0; ni < 4; ++ni) {
                const int row = wc * 64 + ni * 16 + l15;
                bfr[ni] = *(const bf16x8*)(Bs + row * 64 + ((sl0 ^ (row & 7)) * 8));
            }
#pragma unroll
            for (int mi = 0; mi < 4; ++mi)
#pragma unroll
                for (int ni = 0; ni < 4; ++ni)
                    acc[mi][ni] = __builtin_amdgcn_mfma_f32_16x16x32_bf16(af[mi], bfr[ni], acc[mi][ni], 0, 0, 0);
        }
        __syncthreads();
    }

    if (MODE == 0) {
        unsigned short* C = (unsigned short*)Cp;
#pragma unroll
        for (int ni = 0; ni < 4; ++ni) {
            const int col = j0 + wc * 64 + ni * 16 + l15;
            const float bv = (col < bsplit) ? bias[col] : bias2[col - bsplit];
#pragma unroll
            for (int mi = 0; mi < 4; ++mi) {
                const int rb = i0 + wr * 64 + mi * 16 + g * 4;
#pragma unroll
                for (int r = 0; r < 4; ++r)
                    C[(size_t)(rb + r) * N + col] = f2bf(acc[mi][ni][r] + bv);
            }
        }
    } else if (MODE == 1) {
        unsigned short* C = (unsigned short*)Cp + (size_t)bz * sC;
        float cs[4] = {0.f, 0.f, 0.f, 0.f};
#pragma unroll
        for (int ni = 0; ni < 4; ++ni) {
            const int col = j0 + wc * 64 + ni * 16 + l15;
#pragma unroll
            for (int mi = 0; mi < 4; ++mi) {
                const int rb = i0 + wr * 64 + mi * 16 + g * 4;
#pragma unroll
                for (int r = 0; r < 4; ++r) {
                    const float e = __expf(acc[mi][ni][r]);
                    const unsigned short h = f2bf(e);
                    C[(size_t)(rb + r) * N + col] = h;
                    cs[ni] += bf2f(h);   // sum the rounded value: num/denom consistency
                }
            }
        }
#pragma unroll
        for (int ni = 0; ni < 4; ++ni) {
            cs[ni] += __shfl_xor(cs[ni], 16);
            cs[ni] += __shfl_xor(cs[ni], 32);
        }
        if (g == 0) {
#pragma unroll
            for (int ni = 0; ni < 4; ++ni)
                s_red[wr * 128 + wc * 64 + ni * 16 + l15] = cs[ni];
        }
        __syncthreads();
        if (t < 128) {
            const float sp = s_red[t] + s_red[128 + t];
            s_part[((size_t)bz * gy + by) * N + j0 + t] = sp;
        }
    } else {
        float* C = (float*)Cp + (size_t)bz * sC;
#pragma unroll
        for (int ni = 0; ni < 4; ++ni) {
            const int col = j0 + wc * 64 + ni * 16 + l15;
#pragma unroll
            for (int mi = 0; mi < 4; ++mi) {
                const int rb = i0 + wr * 64 + mi * 16 + g * 4;
#pragma unroll
                for (int r = 0; r < 4; ++r)
                    C[(size_t)(rb + r) * N + col] = acc[mi][ni][r];
            }
        }
    }
}

extern "C" void kernel_launch(void* const* d_in, const int* in_sizes, int n_in,
                              void* d_out, int out_size, void* d_ws, size_t ws_size,
                              hipStream_t stream) {
    const float* x  = (const float*)d_in[0];
    const float* Wq = (const float*)d_in[1];
    const float* bq = (const float*)d_in[2];
    const float* Wk = (const float*)d_in[3];
    const float* bk = (const float*)d_in[4];
    float* out = (float*)d_out;

    char* ws = (char*)d_ws;
    unsigned short* xb    = (unsigned short*)(ws);                               // 16 MB
    unsigned short* qk    = (unsigned short*)(ws + (16ull << 20));               // 32 MB [16384][1024]
    unsigned short* WqkT  = (unsigned short*)(ws + (48ull << 20));               // 1 MB [1024][512]
    unsigned short* xsT   = (unsigned short*)(ws + (49ull << 20));               // 16 MB
    float*          s_prt = (float*)(ws + (65ull << 20));                        // 1 MB
    float*          s     = (float*)(ws + (66ull << 20));                        // 64 KB
    unsigned short* expE  = (unsigned short*)(ws + (67ull << 20));               // 64 MB
    if (ws_size < (131ull << 20)) {
        fprintf(stderr, "WS TOO SMALL: have %zu need %llu\n", ws_size, (131ull << 20));
    }

    // 1) xb = bf16(x)
    cast_x_kernel<<<dim3((Bn * Nn * Dn) / (8 * 256)), 256, 0, stream>>>(x, xb, Bn * Nn * Dn);
    // 2) WqkT = bf16([Wq; Wk]^T)  -> [1024][512]
    transpose_cast_kernel<<<dim3(Hn / 64, Dn / 64, 1), 256, 0, stream>>>(Wq, WqkT, nullptr, Dn, Hn);
    transpose_cast_kernel<<<dim3(Hn / 64, Dn / 64, 1), 256, 0, stream>>>(Wk, WqkT + (size_t)Hn * Dn, nullptr, Dn, Hn);
    // 3) qk = xb @ [Wq|Wk] + [bq|bk]   (M=16384, N=1024, K=512)
    {
        const int gx = (2 * Hn) / 128, gy = (Bn * Nn) / 128;  // 8 x 128 = 1024 blocks
        gemm_bt<0><<<dim3(gx * gy), 256, 0, stream>>>(
            xb, 0, Dn, WqkT, 0, Dn, qk, 0, bq, bk, Hn, nullptr,
            Bn * Nn, 2 * Hn, Dn, gx, gy);
    }
    // 4) expE = exp(q @ k^T), s_part (per batch; M=N=2048, K=512)
    {
        const int gx = Nn / 128, gy = Nn / 128;               // 16 x 16 x 8 = 2048 blocks
        gemm_bt<1><<<dim3(gx * gy * Bn), 256, 0, stream>>>(
            qk, (long long)Nn * 2 * Hn, 2 * Hn,               // q = qk[:, 0:512]
            qk + Hn, (long long)Nn * 2 * Hn, 2 * Hn,          // k = qk[:, 512:1024]
            expE, (long long)Nn * Nn, nullptr, nullptr, 0, s_prt,
            Nn, Nn, Hn, gx, gy);
    }
    // 5) s[b][j] = sum of partials
    combine_s_kernel<<<dim3((Bn * Nn) / 256), 256, 0, stream>>>(s_prt, s, Nn / 128, Bn * Nn);
    // 6) xsT[b][d][j] = bf16(x[b][j][d] / s[b][j])
    transpose_cast_kernel<<<dim3(Dn / 64, Nn / 64, Bn), 256, 0, stream>>>(x, xsT, s, Nn, Dn);
    // 7) out = expE @ xsT^T   (per batch; M=2048, N=512, K=2048)
    {
        const int gx = Dn / 128, gy = Nn / 128;               // 4 x 16 x 8 = 512 blocks
        gemm_bt<2><<<dim3(gx * gy * Bn), 256, 0, stream>>>(
            expE, (long long)Nn * Nn, Nn, xsT, (long long)Dn * Nn, Nn,
            out, (long long)Nn * Dn, nullptr, nullptr, 0, nullptr,
            Nn, Dn, Nn, gx, gy);
    }
}